// Round 4
// baseline (1120.723 us; speedup 1.0000x reference)
//
#include <hip/hip_runtime.h>
#include <math.h>

namespace {
constexpr int Vv  = 50257;
constexpr int Dc  = 128;
constexpr int Kc  = 3;
constexpr int NBc = 8;
constexpr int Jc  = 24;      // K*NB
constexpr int Tc  = 64;
constexpr int CHV = 1024;                      // vocab elems per block chunk
constexpr int NCH = (Vv + CHV - 1) / CHV;      // 50
constexpr float INV_SQRT_D = 0.08838834764831845f;
constexpr float DIVW = 2.0f;

// ws layout (float offsets)
constexpr size_t WS_PSI  = 0;        // 24*128
constexpr size_t WS_G    = 4096;     // 24*24 (psi gram)
constexpr size_t WS_BB   = 5120;     // 24*24 (raw bubble gram)
constexpr size_t WS_XN   = 6144;     // 64   |x_t|^2
constexpr size_t WS_BX   = 6400;     // 64*24 bub_j . x_t
constexpr size_t WS_WALL = 8192;     // 64*24
constexpr size_t WS_PART = 12288;    // 64*50*9 = 28800
constexpr size_t WS_LOGZ = 45056;    // 64*4
constexpr size_t WS_P2T  = 65536;    // 24*V  (transposed: [j][v] for coalescing)

// out layout (float offsets), reference return order
constexpr size_t OFF_TOK = 0;
constexpr size_t OFF_RHO = (size_t)Tc * Vv;
constexpr size_t OFF_S   = OFF_RHO + (size_t)Tc * Dc * Dc;
constexpr size_t OFF_H   = OFF_S + Tc;
constexpr size_t OFF_F   = OFF_H + Tc;
constexpr size_t OFF_PF  = OFF_F + Tc;
}

__device__ __forceinline__ float wsum64(float v) {
#pragma unroll
  for (int m = 1; m < 64; m <<= 1) v += __shfl_xor(v, m);
  return v;
}

// online-softmax merge helpers
__device__ __forceinline__ void comb(float& m1, float& s1, float m2, float s2) {
  float M = fmaxf(m1, m2);
  float e1 = (s1 > 0.f) ? expf(m1 - M) : 0.f;
  float e2 = (s2 > 0.f) ? expf(m2 - M) : 0.f;
  s1 = s1 * e1 + s2 * e2;
  m1 = M;
}
__device__ __forceinline__ void comb_sl(float& m1, float& s1, float& sl1,
                                        float m2, float s2, float sl2) {
  float M = fmaxf(m1, m2);
  float e1 = (s1 > 0.f) ? expf(m1 - M) : 0.f;
  float e2 = (s2 > 0.f) ? expf(m2 - M) : 0.f;
  s1 = s1 * e1 + s2 * e2;
  sl1 = sl1 * e1 + sl2 * e2;
  m1 = M;
}

// ---------- psi + psi-Gram G + raw bubble Gram BB ----------
__global__ void k_prep(const float* __restrict__ bub, float* __restrict__ ws) {
  __shared__ float braw[Jc * Dc];
  __shared__ float psi[Jc * Dc];
  __shared__ float nrm[Jc];
  int tid = threadIdx.x;
  for (int i = tid; i < Jc * Dc; i += 256) braw[i] = bub[i];
  __syncthreads();
  if (tid < Jc) {
    float s = 0.f;
    for (int d = 0; d < Dc; ++d) { float b = braw[tid * Dc + d]; s += b * b; }
    nrm[tid] = sqrtf(s) + 1e-10f;
  }
  __syncthreads();
  for (int i = tid; i < Jc * Dc; i += 256) {
    float v = braw[i] / nrm[i / Dc];
    psi[i] = v;
    ws[WS_PSI + i] = v;
  }
  __syncthreads();
  for (int i = tid; i < Jc * Jc; i += 256) {
    int r = i / Jc, c = i % Jc;
    float g = 0.f, b = 0.f;
    for (int d = 0; d < Dc; ++d) {
      g += psi[r * Dc + d] * psi[c * Dc + d];
      b += braw[r * Dc + d] * braw[c * Dc + d];
    }
    ws[WS_G + i] = g;
    ws[WS_BB + i] = b;
  }
}

// ---------- per-token precompute: BX[t][j] = bub_j . E[tok_t], XN[t] = |x|^2 ----------
__global__ void k_tok(const int* __restrict__ tok, const float* __restrict__ E,
                      const float* __restrict__ bub, float* __restrict__ ws) {
  int t = blockIdx.x, lane = threadIdx.x;   // 64 threads = 1 wave
  int tk = tok[t];
  float eA = E[(size_t)tk * Dc + lane];
  float eB = E[(size_t)tk * Dc + 64 + lane];
  float xn = wsum64(eA * eA + eB * eB);
  if (lane == 0) ws[WS_XN + t] = xn;
  float p[Jc];
#pragma unroll
  for (int j = 0; j < Jc; ++j)
    p[j] = bub[j * Dc + lane] * eA + bub[j * Dc + 64 + lane] * eB;
#pragma unroll
  for (int j = 0; j < Jc; ++j) p[j] = wsum64(p[j]);
  if (lane == 0) {
#pragma unroll
    for (int j = 0; j < Jc; ++j) ws[WS_BX + (size_t)t * Jc + j] = p[j];
  }
}

// ---------- sequential recurrence, single wave, register-resident ----------
__global__ void k_recur(const int* __restrict__ tok, const float* __restrict__ E,
                        const float* __restrict__ bub, const float* __restrict__ pdb,
                        const float* __restrict__ psn, float* __restrict__ ws) {
  __shared__ float sBX[Tc * Jc];
  __shared__ float sXN[Tc];
  int lane = threadIdx.x;                 // 64 threads = 1 wave
  for (int i = lane; i < Tc * Jc; i += 64) sBX[i] = ws[WS_BX + i];
  if (lane < Tc) sXN[lane] = ws[WS_XN + lane];
  float db = pdb[0];
  float sens = fabsf(psn[0]);
  int tokv = tok[lane];
  float bubA[Jc], bubB[Jc];
#pragma unroll
  for (int j = 0; j < Jc; ++j) {
    bubA[j] = bub[j * Dc + lane];
    bubB[j] = bub[j * Dc + 64 + lane];
  }
  int jme = (lane < Jc) ? lane : (Jc - 1);
  int kme = jme >> 3;
  float BBrow[Jc];
#pragma unroll
  for (int j = 0; j < Jc; ++j) BBrow[j] = ws[WS_BB + (size_t)jme * Jc + j];
  __syncthreads();
  float mmA[Kc] = {0.f, 0.f, 0.f}, mmB[Kc] = {0.f, 0.f, 0.f};
  float BMv[Kc] = {0.f, 0.f, 0.f};
  int tk0 = __shfl(tokv, 0);
  float xA = E[(size_t)tk0 * Dc + lane];
  float xB = E[(size_t)tk0 * Dc + 64 + lane];
  for (int t = 0; t < Tc; ++t) {
    float nxA = 0.f, nxB = 0.f;
    if (t + 1 < Tc) {
      int nk = __shfl(tokv, t + 1);
      nxA = E[(size_t)nk * Dc + lane];
      nxB = E[(size_t)nk * Dc + 64 + lane];
    }
    float dk[Kc], nk2[Kc];
#pragma unroll
    for (int k = 0; k < Kc; ++k) {
      dk[k]  = wsum64(mmA[k] * xA + mmB[k] * xB);
      nk2[k] = wsum64(mmA[k] * mmA[k] + mmB[k] * mmB[k]);
    }
    float xn = sqrtf(sXN[t]) + 1e-10f;
    float dec[Kc], xmA[Kc], xmB[Kc];
#pragma unroll
    for (int k = 0; k < Kc; ++k) {
      float mn = sqrtf(nk2[k]) + 1e-10f;
      float cosv = dk[k] / (xn * mn);
      float nov = (mn > 1e-8f) ? (1.f - cosv) : 1.f;
      dec[k] = 1.f / (1.f + expf(-(db - sens * nov)));
      xmA[k] = xA + dec[k] * mmA[k];
      xmB[k] = xB + dec[k] * mmB[k];
    }
    float bxj = sBX[t * Jc + jme];
    float decS = (kme == 0) ? dec[0] : ((kme == 1) ? dec[1] : dec[2]);
    float sc = (bxj + decS * BMv[kme]) * (DIVW * INV_SQRT_D);
    float mx = sc;
    mx = fmaxf(mx, __shfl_xor(mx, 1));
    mx = fmaxf(mx, __shfl_xor(mx, 2));
    mx = fmaxf(mx, __shfl_xor(mx, 4));
    float e = expf(sc - mx);
    float ss = e;
    ss += __shfl_xor(ss, 1);
    ss += __shfl_xor(ss, 2);
    ss += __shfl_xor(ss, 4);
    float w = e / ss;
    if (lane < Jc) ws[WS_WALL + (size_t)t * Jc + lane] = w;
    float wj[Jc];
#pragma unroll
    for (int j = 0; j < Jc; ++j) wj[j] = __shfl(w, j);
#pragma unroll
    for (int k = 0; k < Kc; ++k) {
      float accA = 0.f, accB = 0.f;
#pragma unroll
      for (int n = 0; n < NBc; ++n) {
        float om = 1.f - wj[k * NBc + n];
        accA += om * bubA[k * NBc + n];
        accB += om * bubB[k * NBc + n];
      }
      float od8 = (1.f - dec[k]) * 0.125f;
      mmA[k] = dec[k] * mmA[k] + od8 * (xmA[k] + accA);
      mmB[k] = dec[k] * mmB[k] + od8 * (xmB[k] + accB);
    }
#pragma unroll
    for (int k = 0; k < Kc; ++k) {
      float bxm = bxj + dec[k] * BMv[k];
      float s2 = 0.f;
#pragma unroll
      for (int n = 0; n < NBc; ++n) s2 += (1.f - wj[k * NBc + n]) * BBrow[k * NBc + n];
      BMv[k] = dec[k] * BMv[k] + (1.f - dec[k]) * 0.125f * (bxm + s2);
    }
    xA = nxA; xB = nxB;
  }
}

// ---------- P2T[j][v] = (E[v] . psi_j)^2 ----------
__global__ void k_proj(const float* __restrict__ E, float* __restrict__ ws) {
  __shared__ float4 psi4[Jc][Dc / 4];
  int tid = threadIdx.x;
  for (int i = tid; i < Jc * Dc / 4; i += 256)
    ((float4*)psi4)[i] = ((const float4*)(ws + WS_PSI))[i];
  __syncthreads();
  int v = blockIdx.x * 256 + tid;
  if (v >= Vv) return;
  float acc[Jc];
#pragma unroll
  for (int j = 0; j < Jc; ++j) acc[j] = 0.f;
  const float4* e4 = (const float4*)(E + (size_t)v * Dc);
  for (int d = 0; d < Dc / 4; ++d) {
    float4 e = e4[d];
#pragma unroll
    for (int j = 0; j < Jc; ++j) {
      float4 p = psi4[j][d];
      acc[j] += e.x * p.x + e.y * p.y + e.z * p.z + e.w * p.w;
    }
  }
#pragma unroll
  for (int j = 0; j < Jc; ++j) ws[WS_P2T + (size_t)j * Vv + v] = acc[j] * acc[j];
}

// ---------- rho[t] = sum_j (w_j/3) psi_j psi_j^T  (one block per t) ----------
__global__ void k_rho(const float* __restrict__ ws, float* __restrict__ out) {
  int t = blockIdx.x;
  __shared__ float psis[Jc * Dc];
  __shared__ float wsh[Jc];
  int tid = threadIdx.x;
  for (int i = tid; i < Jc * Dc; i += 256) psis[i] = ws[WS_PSI + i];
  if (tid < Jc) wsh[tid] = ws[WS_WALL + (size_t)t * Jc + tid] * (1.f / 3.f);
  __syncthreads();
  int d = tid >> 1, eh = (tid & 1) * 64;
  float4 acc[16];
#pragma unroll
  for (int i = 0; i < 16; ++i) acc[i] = make_float4(0.f, 0.f, 0.f, 0.f);
  for (int j = 0; j < Jc; ++j) {
    float a = wsh[j] * psis[j * Dc + d];
    const float4* pr = (const float4*)&psis[j * Dc + eh];
#pragma unroll
    for (int i = 0; i < 16; ++i) {
      float4 p = pr[i];
      acc[i].x += a * p.x; acc[i].y += a * p.y; acc[i].z += a * p.z; acc[i].w += a * p.w;
    }
  }
  float* o = out + OFF_RHO + (size_t)t * Dc * Dc + (size_t)d * Dc + eh;
#pragma unroll
  for (int i = 0; i < 16; ++i) ((float4*)o)[i] = acc[i];
}

// ---------- S_rho[t]: one-sided Jacobi on C = Psi*diag(sqrt(w/3)), registers only ----------
// M = C^T C has rho's nonzero eigenvalues. Columns in registers (lane holds dims
// lane, lane+64). Brent-Luk tournament schedule: pairs always (top_i, bottom_i)
// at STATIC slots; columns rotate through slots with static v_movs. Norms kept
// analytically (exact 2x2 Jacobi iterates) - no LDS, no ds_bpermute in the loop.
__global__ void k_eig(const float* __restrict__ ws, float* __restrict__ out) {
  int t = blockIdx.x;
  int lane = threadIdx.x;              // 64 threads = 1 wave
  float TA[12], TB[12], Tn[12], BA[12], BB[12], Bn[12];
#pragma unroll
  for (int i = 0; i < 12; ++i) {
    int j0 = 2 * i, j1 = 2 * i + 1;
    float w0 = ws[WS_WALL + (size_t)t * Jc + j0] * (1.f / 3.f);
    float w1 = ws[WS_WALL + (size_t)t * Jc + j1] * (1.f / 3.f);
    float s0 = sqrtf(w0), s1 = sqrtf(w1);
    TA[i] = ws[WS_PSI + j0 * Dc + lane] * s0;
    TB[i] = ws[WS_PSI + j0 * Dc + 64 + lane] * s0;
    BA[i] = ws[WS_PSI + j1 * Dc + lane] * s1;
    BB[i] = ws[WS_PSI + j1 * Dc + 64 + lane] * s1;
    Tn[i] = w0; Bn[i] = w1;
  }
  for (int sweep = 0; sweep < 7; ++sweep) {
    for (int rr = 0; rr < 23; ++rr) {
#pragma unroll
      for (int i = 0; i < 12; ++i) {
        float apq = wsum64(TA[i] * BA[i] + TB[i] * BB[i]);
        // apq bit-identical across lanes -> wave-uniform branch
        if (fabsf(apq) > 1e-11f) {
          float app = Tn[i], aqq = Bn[i];
          float th = (aqq - app) / (2.f * apq);
          float tt = 1.f / (fabsf(th) + sqrtf(1.f + th * th));
          if (th < 0.f) tt = -tt;
          float c = 1.f / sqrtf(1.f + tt * tt);
          float s = tt * c;
          float ta = TA[i], tb = TB[i], ba = BA[i], bb = BB[i];
          TA[i] = c * ta - s * ba; BA[i] = s * ta + c * ba;
          TB[i] = c * tb - s * bb; BB[i] = s * tb + c * bb;
          Tn[i] = app - tt * apq;  Bn[i] = aqq + tt * apq;
        }
      }
      // Brent-Luk rotation: top0 fixed; top shifts right, bottom shifts left
      float tA = TA[11], tB = TB[11], tN = Tn[11];
#pragma unroll
      for (int i = 11; i >= 2; --i) { TA[i] = TA[i-1]; TB[i] = TB[i-1]; Tn[i] = Tn[i-1]; }
      TA[1] = BA[0]; TB[1] = BB[0]; Tn[1] = Bn[0];
#pragma unroll
      for (int i = 0; i <= 10; ++i) { BA[i] = BA[i+1]; BB[i] = BB[i+1]; Bn[i] = Bn[i+1]; }
      BA[11] = tA; BB[11] = tB; Bn[11] = tN;
    }
  }
  // entropy of {24 norms} U {104 x 1e-12 clipped zeros}
  float lam[Jc];
#pragma unroll
  for (int i = 0; i < 12; ++i) { lam[i] = fmaxf(Tn[i], 1e-12f); lam[12 + i] = fmaxf(Bn[i], 1e-12f); }
  float tot = 0.f;
#pragma unroll
  for (int i = 0; i < Jc; ++i) tot += lam[i];
  tot += (float)(Dc - Jc) * 1e-12f;
  float acc = 0.f;
#pragma unroll
  for (int i = 0; i < Jc; ++i) { float p = lam[i] / tot; acc += p * logf(p); }
  float pe = 1e-12f / tot;
  acc += (float)(Dc - Jc) * pe * logf(pe);
  if (lane == 0) out[OFF_S + t] = -acc;
}

// ---------- logits (stored into d_out prob regions) + online-softmax partials ----------
__global__ void k_logits(float* __restrict__ ws, float* __restrict__ out) {
  int ch = blockIdx.x, t = blockIdx.y, tid = threadIdx.x;
  __shared__ float wsh[Jc];
  __shared__ float rm[4][4], rs[4][4], rsl2[4];
  if (tid < Jc) wsh[tid] = ws[WS_WALL + (size_t)t * Jc + tid];
  __syncthreads();
  float m[4] = {-INFINITY, -INFINITY, -INFINITY, -INFINITY};
  float s[4] = {0.f, 0.f, 0.f, 0.f};
  float sl = 0.f;
  const float* p2 = ws + WS_P2T;
  for (int r = 0; r < 4; ++r) {
    int v = ch * CHV + r * 256 + tid;
    if (v >= Vv) break;
    float l0 = 0.f, l1 = 0.f, l2 = 0.f;
#pragma unroll
    for (int n = 0; n < NBc; ++n) {
      l0 += wsh[n]      * p2[(size_t)n * Vv + v];
      l1 += wsh[8 + n]  * p2[(size_t)(8 + n) * Vv + v];
      l2 += wsh[16 + n] * p2[(size_t)(16 + n) * Vv + v];
    }
    float l[4] = { l0, l1, l2, (l0 + l1 + l2) * (1.f / 3.f) };
    out[OFF_TOK + (size_t)t * Vv + v] = l[3];
    out[OFF_PF + ((size_t)t * Kc + 0) * Vv + v] = l0;
    out[OFF_PF + ((size_t)t * Kc + 1) * Vv + v] = l1;
    out[OFF_PF + ((size_t)t * Kc + 2) * Vv + v] = l2;
#pragma unroll
    for (int d = 0; d < 4; ++d) {
      float li = l[d];
      if (li > m[d]) {
        float e = expf(m[d] - li);
        s[d] = s[d] * e + 1.f;
        if (d == 3) sl = sl * e + li;
        m[d] = li;
      } else {
        float e = expf(li - m[d]);
        s[d] += e;
        if (d == 3) sl += e * li;
      }
    }
  }
#pragma unroll
  for (int off = 32; off; off >>= 1) {
#pragma unroll
    for (int d = 0; d < 3; ++d) {
      float om = __shfl_down(m[d], off);
      float os = __shfl_down(s[d], off);
      comb(m[d], s[d], om, os);
    }
    float om = __shfl_down(m[3], off);
    float os = __shfl_down(s[3], off);
    float osl = __shfl_down(sl, off);
    comb_sl(m[3], s[3], sl, om, os, osl);
  }
  int wv = tid >> 6, ln = tid & 63;
  if (ln == 0) {
#pragma unroll
    for (int d = 0; d < 4; ++d) { rm[wv][d] = m[d]; rs[wv][d] = s[d]; }
    rsl2[wv] = sl;
  }
  __syncthreads();
  if (tid == 0) {
    float* part = ws + WS_PART + ((size_t)t * NCH + ch) * 9;
    for (int d = 0; d < 3; ++d) {
      float M = rm[0][d], S = rs[0][d];
      for (int w2 = 1; w2 < 4; ++w2) comb(M, S, rm[w2][d], rs[w2][d]);
      part[d] = M; part[4 + d] = S;
    }
    float M = rm[0][3], S = rs[0][3], SL = rsl2[0];
    for (int w2 = 1; w2 < 4; ++w2) comb_sl(M, S, SL, rm[w2][3], rs[w2][3], rsl2[w2]);
    part[3] = M; part[7] = S; part[8] = SL;
  }
}

// ---------- merge chunk partials -> logZ[t][4]; H, F ----------
__global__ void k_reduce(float* __restrict__ ws, float* __restrict__ out) {
  int t = blockIdx.x, tid = threadIdx.x;
  if (tid < 4) {
    float M = -INFINITY, S = 0.f, SL = 0.f;
    for (int ch = 0; ch < NCH; ++ch) {
      const float* p = ws + WS_PART + ((size_t)t * NCH + ch) * 9;
      if (tid == 3) comb_sl(M, S, SL, p[3], p[7], p[8]);
      else          comb(M, S, p[tid], p[4 + tid]);
    }
    float lz = M + logf(S);
    ws[WS_LOGZ + (size_t)t * 4 + tid] = lz;
    if (tid == 3) {
      float H = lz - SL / S;
      float Srho = out[OFF_S + t];
      out[OFF_H + t] = H;
      out[OFF_F + t] = H - Srho;
    }
  }
}

// ---------- in-place logits -> probs ----------
__global__ void k_norm(const float* __restrict__ ws, float* __restrict__ out, int foam) {
  int row = blockIdx.y, ch = blockIdx.x, tid = threadIdx.x;
  size_t base; int lzi;
  if (foam) { int t = row / Kc, k = row % Kc; base = OFF_PF + (size_t)row * Vv; lzi = t * 4 + k; }
  else { base = OFF_TOK + (size_t)row * Vv; lzi = row * 4 + 3; }
  float lz = ws[WS_LOGZ + lzi];
  for (int r = 0; r < 4; ++r) {
    int v = ch * CHV + r * 256 + tid;
    if (v < Vv) out[base + v] = expf(out[base + v] - lz);
  }
}

extern "C" void kernel_launch(void* const* d_in, const int* in_sizes, int n_in,
                              void* d_out, int out_size, void* d_ws, size_t ws_size,
                              hipStream_t stream) {
  const int*   tokens = (const int*)d_in[0];
  const float* E      = (const float*)d_in[1];
  const float* bub    = (const float*)d_in[2];
  const float* pdb    = (const float*)d_in[3];
  const float* psn    = (const float*)d_in[4];
  float* out = (float*)d_out;
  float* ws  = (float*)d_ws;

  k_prep<<<1, 256, 0, stream>>>(bub, ws);
  k_proj<<<(Vv + 255) / 256, 256, 0, stream>>>(E, ws);
  k_tok<<<Tc, 64, 0, stream>>>(tokens, E, bub, ws);
  k_recur<<<1, 64, 0, stream>>>(tokens, E, bub, pdb, psn, ws);
  k_rho<<<Tc, 256, 0, stream>>>(ws, out);
  k_eig<<<Tc, 64, 0, stream>>>(ws, out);
  k_logits<<<dim3(NCH, Tc), 256, 0, stream>>>(ws, out);
  k_reduce<<<Tc, 64, 0, stream>>>(ws, out);
  k_norm<<<dim3(NCH, Tc), 256, 0, stream>>>(ws, out, 0);
  k_norm<<<dim3(NCH, Tc * Kc), 256, 0, stream>>>(ws, out, 1);
}

// Round 5
// 844.546 us; speedup vs baseline: 1.3270x; 1.3270x over previous
//
#include <hip/hip_runtime.h>
#include <math.h>

namespace {
constexpr int Vv  = 50257;
constexpr int Dc  = 128;
constexpr int Kc  = 3;
constexpr int NBc = 8;
constexpr int Jc  = 24;      // K*NB
constexpr int Tc  = 64;
constexpr int CHV = 1024;                      // vocab elems per block chunk
constexpr int NCH = (Vv + CHV - 1) / CHV;      // 50
constexpr float INV_SQRT_D = 0.08838834764831845f;
constexpr float DIVW = 2.0f;

// ws layout (float offsets)
constexpr size_t WS_PSI  = 0;        // 24*128
constexpr size_t WS_G    = 4096;     // 24*24 (psi gram)
constexpr size_t WS_BB   = 5120;     // 24*24 (raw bubble gram)
constexpr size_t WS_XN   = 6144;     // 64   |x_t|^2
constexpr size_t WS_BX   = 6400;     // 64*24 bub_j . x_t
constexpr size_t WS_WALL = 8192;     // 64*24
constexpr size_t WS_PART = 12288;    // 64*50*9 = 28800
constexpr size_t WS_LOGZ = 45056;    // 64*4
constexpr size_t WS_P2T  = 65536;    // 24*V  (transposed: [j][v] for coalescing)

// out layout (float offsets), reference return order
constexpr size_t OFF_TOK = 0;
constexpr size_t OFF_RHO = (size_t)Tc * Vv;
constexpr size_t OFF_S   = OFF_RHO + (size_t)Tc * Dc * Dc;
constexpr size_t OFF_H   = OFF_S + Tc;
constexpr size_t OFF_F   = OFF_H + Tc;
constexpr size_t OFF_PF  = OFF_F + Tc;
}

__device__ __forceinline__ float wsum64(float v) {
#pragma unroll
  for (int m = 1; m < 64; m <<= 1) v += __shfl_xor(v, m);
  return v;
}

// online-softmax merge helpers
__device__ __forceinline__ void comb(float& m1, float& s1, float m2, float s2) {
  float M = fmaxf(m1, m2);
  float e1 = (s1 > 0.f) ? expf(m1 - M) : 0.f;
  float e2 = (s2 > 0.f) ? expf(m2 - M) : 0.f;
  s1 = s1 * e1 + s2 * e2;
  m1 = M;
}
__device__ __forceinline__ void comb_sl(float& m1, float& s1, float& sl1,
                                        float m2, float s2, float sl2) {
  float M = fmaxf(m1, m2);
  float e1 = (s1 > 0.f) ? expf(m1 - M) : 0.f;
  float e2 = (s2 > 0.f) ? expf(m2 - M) : 0.f;
  s1 = s1 * e1 + s2 * e2;
  sl1 = sl1 * e1 + sl2 * e2;
  m1 = M;
}

// ---------- psi + psi-Gram G + raw bubble Gram BB ----------
__global__ void k_prep(const float* __restrict__ bub, float* __restrict__ ws) {
  __shared__ float braw[Jc * Dc];
  __shared__ float psi[Jc * Dc];
  __shared__ float nrm[Jc];
  int tid = threadIdx.x;
  for (int i = tid; i < Jc * Dc; i += 256) braw[i] = bub[i];
  __syncthreads();
  if (tid < Jc) {
    float s = 0.f;
    for (int d = 0; d < Dc; ++d) { float b = braw[tid * Dc + d]; s += b * b; }
    nrm[tid] = sqrtf(s) + 1e-10f;
  }
  __syncthreads();
  for (int i = tid; i < Jc * Dc; i += 256) {
    float v = braw[i] / nrm[i / Dc];
    psi[i] = v;
    ws[WS_PSI + i] = v;
  }
  __syncthreads();
  for (int i = tid; i < Jc * Jc; i += 256) {
    int r = i / Jc, c = i % Jc;
    float g = 0.f, b = 0.f;
    for (int d = 0; d < Dc; ++d) {
      g += psi[r * Dc + d] * psi[c * Dc + d];
      b += braw[r * Dc + d] * braw[c * Dc + d];
    }
    ws[WS_G + i] = g;
    ws[WS_BB + i] = b;
  }
}

// ---------- per-token precompute: BX[t][j] = bub_j . E[tok_t], XN[t] = |x|^2 ----------
__global__ void __launch_bounds__(64, 1)
k_tok(const int* __restrict__ tok, const float* __restrict__ E,
      const float* __restrict__ bub, float* __restrict__ ws) {
  int t = blockIdx.x, lane = threadIdx.x;   // 64 threads = 1 wave
  int tk = tok[t];
  float eA = E[(size_t)tk * Dc + lane];
  float eB = E[(size_t)tk * Dc + 64 + lane];
  float xn = wsum64(eA * eA + eB * eB);
  if (lane == 0) ws[WS_XN + t] = xn;
  float p[Jc];
#pragma unroll
  for (int j = 0; j < Jc; ++j)
    p[j] = bub[j * Dc + lane] * eA + bub[j * Dc + 64 + lane] * eB;
#pragma unroll
  for (int m = 1; m < 64; m <<= 1) {
#pragma unroll
    for (int j = 0; j < Jc; ++j) p[j] += __shfl_xor(p[j], m);
  }
  if (lane == 0) {
#pragma unroll
    for (int j = 0; j < Jc; ++j) ws[WS_BX + (size_t)t * Jc + j] = p[j];
  }
}

// ---------- sequential recurrence, single wave, register-resident ----------
__global__ void __launch_bounds__(64, 1)
k_recur(const int* __restrict__ tok, const float* __restrict__ E,
        const float* __restrict__ bub, const float* __restrict__ pdb,
        const float* __restrict__ psn, float* __restrict__ ws) {
  __shared__ float sBX[Tc * Jc];
  __shared__ float sXN[Tc];
  int lane = threadIdx.x;                 // 64 threads = 1 wave
  for (int i = lane; i < Tc * Jc; i += 64) sBX[i] = ws[WS_BX + i];
  if (lane < Tc) sXN[lane] = ws[WS_XN + lane];
  float db = pdb[0];
  float sens = fabsf(psn[0]);
  int tokv = tok[lane];
  float bubA[Jc], bubB[Jc];
#pragma unroll
  for (int j = 0; j < Jc; ++j) {
    bubA[j] = bub[j * Dc + lane];
    bubB[j] = bub[j * Dc + 64 + lane];
  }
  int jme = (lane < Jc) ? lane : (Jc - 1);
  int kme = jme >> 3;
  float BBrow[Jc];
#pragma unroll
  for (int j = 0; j < Jc; ++j) BBrow[j] = ws[WS_BB + (size_t)jme * Jc + j];
  __syncthreads();
  float mmA[Kc] = {0.f, 0.f, 0.f}, mmB[Kc] = {0.f, 0.f, 0.f};
  float BMv[Kc] = {0.f, 0.f, 0.f};
  int tk0 = __shfl(tokv, 0);
  float xA = E[(size_t)tk0 * Dc + lane];
  float xB = E[(size_t)tk0 * Dc + 64 + lane];
  for (int t = 0; t < Tc; ++t) {
    float nxA = 0.f, nxB = 0.f;
    if (t + 1 < Tc) {
      int nk = __shfl(tokv, t + 1);
      nxA = E[(size_t)nk * Dc + lane];
      nxB = E[(size_t)nk * Dc + 64 + lane];
    }
    float dk[Kc], nk2[Kc];
#pragma unroll
    for (int k = 0; k < Kc; ++k) {
      dk[k]  = mmA[k] * xA + mmB[k] * xB;
      nk2[k] = mmA[k] * mmA[k] + mmB[k] * mmB[k];
    }
#pragma unroll
    for (int m = 1; m < 64; m <<= 1) {
#pragma unroll
      for (int k = 0; k < Kc; ++k) {
        dk[k]  += __shfl_xor(dk[k], m);
        nk2[k] += __shfl_xor(nk2[k], m);
      }
    }
    float xn = sqrtf(sXN[t]) + 1e-10f;
    float dec[Kc], xmA[Kc], xmB[Kc];
#pragma unroll
    for (int k = 0; k < Kc; ++k) {
      float mn = sqrtf(nk2[k]) + 1e-10f;
      float cosv = dk[k] / (xn * mn);
      float nov = (mn > 1e-8f) ? (1.f - cosv) : 1.f;
      dec[k] = 1.f / (1.f + expf(-(db - sens * nov)));
      xmA[k] = xA + dec[k] * mmA[k];
      xmB[k] = xB + dec[k] * mmB[k];
    }
    float bxj = sBX[t * Jc + jme];
    float decS = (kme == 0) ? dec[0] : ((kme == 1) ? dec[1] : dec[2]);
    float sc = (bxj + decS * BMv[kme]) * (DIVW * INV_SQRT_D);
    float mx = sc;
    mx = fmaxf(mx, __shfl_xor(mx, 1));
    mx = fmaxf(mx, __shfl_xor(mx, 2));
    mx = fmaxf(mx, __shfl_xor(mx, 4));
    float e = expf(sc - mx);
    float ss = e;
    ss += __shfl_xor(ss, 1);
    ss += __shfl_xor(ss, 2);
    ss += __shfl_xor(ss, 4);
    float w = e / ss;
    if (lane < Jc) ws[WS_WALL + (size_t)t * Jc + lane] = w;
    float wj[Jc];
#pragma unroll
    for (int j = 0; j < Jc; ++j) wj[j] = __shfl(w, j);
#pragma unroll
    for (int k = 0; k < Kc; ++k) {
      float accA = 0.f, accB = 0.f;
#pragma unroll
      for (int n = 0; n < NBc; ++n) {
        float om = 1.f - wj[k * NBc + n];
        accA += om * bubA[k * NBc + n];
        accB += om * bubB[k * NBc + n];
      }
      float od8 = (1.f - dec[k]) * 0.125f;
      mmA[k] = dec[k] * mmA[k] + od8 * (xmA[k] + accA);
      mmB[k] = dec[k] * mmB[k] + od8 * (xmB[k] + accB);
    }
#pragma unroll
    for (int k = 0; k < Kc; ++k) {
      float bxm = bxj + dec[k] * BMv[k];
      float s2 = 0.f;
#pragma unroll
      for (int n = 0; n < NBc; ++n) s2 += (1.f - wj[k * NBc + n]) * BBrow[k * NBc + n];
      BMv[k] = dec[k] * BMv[k] + (1.f - dec[k]) * 0.125f * (bxm + s2);
    }
    xA = nxA; xB = nxB;
  }
}

// ---------- P2T[j][v] = (E[v] . psi_j)^2 ----------
__global__ void k_proj(const float* __restrict__ E, float* __restrict__ ws) {
  __shared__ float4 psi4[Jc][Dc / 4];
  int tid = threadIdx.x;
  for (int i = tid; i < Jc * Dc / 4; i += 256)
    ((float4*)psi4)[i] = ((const float4*)(ws + WS_PSI))[i];
  __syncthreads();
  int v = blockIdx.x * 256 + tid;
  if (v >= Vv) return;
  float acc[Jc];
#pragma unroll
  for (int j = 0; j < Jc; ++j) acc[j] = 0.f;
  const float4* e4 = (const float4*)(E + (size_t)v * Dc);
  for (int d = 0; d < Dc / 4; ++d) {
    float4 e = e4[d];
#pragma unroll
    for (int j = 0; j < Jc; ++j) {
      float4 p = psi4[j][d];
      acc[j] += e.x * p.x + e.y * p.y + e.z * p.z + e.w * p.w;
    }
  }
#pragma unroll
  for (int j = 0; j < Jc; ++j) ws[WS_P2T + (size_t)j * Vv + v] = acc[j] * acc[j];
}

// ---------- rho[t] = sum_j (w_j/3) psi_j psi_j^T  (one block per t) ----------
__global__ void k_rho(const float* __restrict__ ws, float* __restrict__ out) {
  int t = blockIdx.x;
  __shared__ float psis[Jc * Dc];
  __shared__ float wsh[Jc];
  int tid = threadIdx.x;
  for (int i = tid; i < Jc * Dc; i += 256) psis[i] = ws[WS_PSI + i];
  if (tid < Jc) wsh[tid] = ws[WS_WALL + (size_t)t * Jc + tid] * (1.f / 3.f);
  __syncthreads();
  int d = tid >> 1, eh = (tid & 1) * 64;
  float4 acc[16];
#pragma unroll
  for (int i = 0; i < 16; ++i) acc[i] = make_float4(0.f, 0.f, 0.f, 0.f);
  for (int j = 0; j < Jc; ++j) {
    float a = wsh[j] * psis[j * Dc + d];
    const float4* pr = (const float4*)&psis[j * Dc + eh];
#pragma unroll
    for (int i = 0; i < 16; ++i) {
      float4 p = pr[i];
      acc[i].x += a * p.x; acc[i].y += a * p.y; acc[i].z += a * p.z; acc[i].w += a * p.w;
    }
  }
  float* o = out + OFF_RHO + (size_t)t * Dc * Dc + (size_t)d * Dc + eh;
#pragma unroll
  for (int i = 0; i < 16; ++i) ((float4*)o)[i] = acc[i];
}

// ---------- S_rho[t]: one-sided Jacobi on C = Psi*diag(sqrt(w/3)), registers only ----------
// Brent-Luk tournament: pairs at static slots, columns rotate via static movs.
// __launch_bounds__(64,1): full VGPR budget (state = 72 floats) -> NO spill.
// All 12 pair-dots reduced in one batched butterfly (ILP across pairs);
// rotation is branchless selects.
__global__ void __launch_bounds__(64, 1)
k_eig(const float* __restrict__ ws, float* __restrict__ out) {
  int t = blockIdx.x;
  int lane = threadIdx.x;              // 64 threads = 1 wave
  float TA[12], TB[12], Tn[12], BA[12], BB[12], Bn[12];
#pragma unroll
  for (int i = 0; i < 12; ++i) {
    int j0 = 2 * i, j1 = 2 * i + 1;
    float w0 = ws[WS_WALL + (size_t)t * Jc + j0] * (1.f / 3.f);
    float w1 = ws[WS_WALL + (size_t)t * Jc + j1] * (1.f / 3.f);
    float s0 = sqrtf(w0), s1 = sqrtf(w1);
    TA[i] = ws[WS_PSI + j0 * Dc + lane] * s0;
    TB[i] = ws[WS_PSI + j0 * Dc + 64 + lane] * s0;
    BA[i] = ws[WS_PSI + j1 * Dc + lane] * s1;
    BB[i] = ws[WS_PSI + j1 * Dc + 64 + lane] * s1;
    Tn[i] = w0; Bn[i] = w1;
  }
  for (int sweep = 0; sweep < 7; ++sweep) {
    for (int rr = 0; rr < 23; ++rr) {
      float apq[12];
#pragma unroll
      for (int i = 0; i < 12; ++i) apq[i] = TA[i] * BA[i] + TB[i] * BB[i];
#pragma unroll
      for (int m = 1; m < 64; m <<= 1) {
#pragma unroll
        for (int i = 0; i < 12; ++i) apq[i] += __shfl_xor(apq[i], m);
      }
#pragma unroll
      for (int i = 0; i < 12; ++i) {
        float a = apq[i];
        float app = Tn[i], aqq = Bn[i];
        float den = 2.f * a;
        den = (fabsf(den) < 1e-30f) ? 1e-30f : den;
        float th = (aqq - app) / den;
        float tt = 1.f / (fabsf(th) + sqrtf(1.f + th * th));
        tt = (th < 0.f) ? -tt : tt;
        bool skip = fabsf(a) < 1e-12f;
        float c = skip ? 1.f : (1.f / sqrtf(1.f + tt * tt));
        float s = skip ? 0.f : tt * c;
        float tadj = skip ? 0.f : tt;
        float ta = TA[i], tb = TB[i], ba = BA[i], bb = BB[i];
        TA[i] = c * ta - s * ba; BA[i] = s * ta + c * ba;
        TB[i] = c * tb - s * bb; BB[i] = s * tb + c * bb;
        Tn[i] = app - tadj * a;  Bn[i] = aqq + tadj * a;
      }
      // Brent-Luk rotation: top0 fixed; top shifts right, bottom shifts left
      float tA = TA[11], tB = TB[11], tN = Tn[11];
#pragma unroll
      for (int i = 11; i >= 2; --i) { TA[i] = TA[i-1]; TB[i] = TB[i-1]; Tn[i] = Tn[i-1]; }
      TA[1] = BA[0]; TB[1] = BB[0]; Tn[1] = Bn[0];
#pragma unroll
      for (int i = 0; i <= 10; ++i) { BA[i] = BA[i+1]; BB[i] = BB[i+1]; Bn[i] = Bn[i+1]; }
      BA[11] = tA; BB[11] = tB; Bn[11] = tN;
    }
  }
  // entropy of {24 norms} U {104 x 1e-12 clipped zeros}
  float lam[Jc];
#pragma unroll
  for (int i = 0; i < 12; ++i) { lam[i] = fmaxf(Tn[i], 1e-12f); lam[12 + i] = fmaxf(Bn[i], 1e-12f); }
  float tot = 0.f;
#pragma unroll
  for (int i = 0; i < Jc; ++i) tot += lam[i];
  tot += (float)(Dc - Jc) * 1e-12f;
  float acc = 0.f;
#pragma unroll
  for (int i = 0; i < Jc; ++i) { float p = lam[i] / tot; acc += p * logf(p); }
  float pe = 1e-12f / tot;
  acc += (float)(Dc - Jc) * pe * logf(pe);
  if (lane == 0) out[OFF_S + t] = -acc;
}

// ---------- logits (stored into d_out prob regions) + online-softmax partials ----------
__global__ void k_logits(float* __restrict__ ws, float* __restrict__ out) {
  int ch = blockIdx.x, t = blockIdx.y, tid = threadIdx.x;
  __shared__ float wsh[Jc];
  __shared__ float rm[4][4], rs[4][4], rsl2[4];
  if (tid < Jc) wsh[tid] = ws[WS_WALL + (size_t)t * Jc + tid];
  __syncthreads();
  float m[4] = {-INFINITY, -INFINITY, -INFINITY, -INFINITY};
  float s[4] = {0.f, 0.f, 0.f, 0.f};
  float sl = 0.f;
  const float* p2 = ws + WS_P2T;
  for (int r = 0; r < 4; ++r) {
    int v = ch * CHV + r * 256 + tid;
    if (v >= Vv) break;
    float l0 = 0.f, l1 = 0.f, l2 = 0.f;
#pragma unroll
    for (int n = 0; n < NBc; ++n) {
      l0 += wsh[n]      * p2[(size_t)n * Vv + v];
      l1 += wsh[8 + n]  * p2[(size_t)(8 + n) * Vv + v];
      l2 += wsh[16 + n] * p2[(size_t)(16 + n) * Vv + v];
    }
    float l[4] = { l0, l1, l2, (l0 + l1 + l2) * (1.f / 3.f) };
    out[OFF_TOK + (size_t)t * Vv + v] = l[3];
    out[OFF_PF + ((size_t)t * Kc + 0) * Vv + v] = l0;
    out[OFF_PF + ((size_t)t * Kc + 1) * Vv + v] = l1;
    out[OFF_PF + ((size_t)t * Kc + 2) * Vv + v] = l2;
#pragma unroll
    for (int d = 0; d < 4; ++d) {
      float li = l[d];
      if (li > m[d]) {
        float e = expf(m[d] - li);
        s[d] = s[d] * e + 1.f;
        if (d == 3) sl = sl * e + li;
        m[d] = li;
      } else {
        float e = expf(li - m[d]);
        s[d] += e;
        if (d == 3) sl += e * li;
      }
    }
  }
#pragma unroll
  for (int off = 32; off; off >>= 1) {
#pragma unroll
    for (int d = 0; d < 3; ++d) {
      float om = __shfl_down(m[d], off);
      float os = __shfl_down(s[d], off);
      comb(m[d], s[d], om, os);
    }
    float om = __shfl_down(m[3], off);
    float os = __shfl_down(s[3], off);
    float osl = __shfl_down(sl, off);
    comb_sl(m[3], s[3], sl, om, os, osl);
  }
  int wv = tid >> 6, ln = tid & 63;
  if (ln == 0) {
#pragma unroll
    for (int d = 0; d < 4; ++d) { rm[wv][d] = m[d]; rs[wv][d] = s[d]; }
    rsl2[wv] = sl;
  }
  __syncthreads();
  if (tid == 0) {
    float* part = ws + WS_PART + ((size_t)t * NCH + ch) * 9;
    for (int d = 0; d < 3; ++d) {
      float M = rm[0][d], S = rs[0][d];
      for (int w2 = 1; w2 < 4; ++w2) comb(M, S, rm[w2][d], rs[w2][d]);
      part[d] = M; part[4 + d] = S;
    }
    float M = rm[0][3], S = rs[0][3], SL = rsl2[0];
    for (int w2 = 1; w2 < 4; ++w2) comb_sl(M, S, SL, rm[w2][3], rs[w2][3], rsl2[w2]);
    part[3] = M; part[7] = S; part[8] = SL;
  }
}

// ---------- merge chunk partials -> logZ[t][4]; H, F ----------
__global__ void k_reduce(float* __restrict__ ws, float* __restrict__ out) {
  int t = blockIdx.x, tid = threadIdx.x;
  if (tid < 4) {
    float M = -INFINITY, S = 0.f, SL = 0.f;
    for (int ch = 0; ch < NCH; ++ch) {
      const float* p = ws + WS_PART + ((size_t)t * NCH + ch) * 9;
      if (tid == 3) comb_sl(M, S, SL, p[3], p[7], p[8]);
      else          comb(M, S, p[tid], p[4 + tid]);
    }
    float lz = M + logf(S);
    ws[WS_LOGZ + (size_t)t * 4 + tid] = lz;
    if (tid == 3) {
      float H = lz - SL / S;
      float Srho = out[OFF_S + t];
      out[OFF_H + t] = H;
      out[OFF_F + t] = H - Srho;
    }
  }
}

// ---------- in-place logits -> probs ----------
__global__ void k_norm(const float* __restrict__ ws, float* __restrict__ out, int foam) {
  int row = blockIdx.y, ch = blockIdx.x, tid = threadIdx.x;
  size_t base; int lzi;
  if (foam) { int t = row / Kc, k = row % Kc; base = OFF_PF + (size_t)row * Vv; lzi = t * 4 + k; }
  else { base = OFF_TOK + (size_t)row * Vv; lzi = row * 4 + 3; }
  float lz = ws[WS_LOGZ + lzi];
  for (int r = 0; r < 4; ++r) {
    int v = ch * CHV + r * 256 + tid;
    if (v < Vv) out[base + v] = expf(out[base + v] - lz);
  }
}

extern "C" void kernel_launch(void* const* d_in, const int* in_sizes, int n_in,
                              void* d_out, int out_size, void* d_ws, size_t ws_size,
                              hipStream_t stream) {
  const int*   tokens = (const int*)d_in[0];
  const float* E      = (const float*)d_in[1];
  const float* bub    = (const float*)d_in[2];
  const float* pdb    = (const float*)d_in[3];
  const float* psn    = (const float*)d_in[4];
  float* out = (float*)d_out;
  float* ws  = (float*)d_ws;

  k_prep<<<1, 256, 0, stream>>>(bub, ws);
  k_proj<<<(Vv + 255) / 256, 256, 0, stream>>>(E, ws);
  k_tok<<<Tc, 64, 0, stream>>>(tokens, E, bub, ws);
  k_recur<<<1, 64, 0, stream>>>(tokens, E, bub, pdb, psn, ws);
  k_rho<<<Tc, 256, 0, stream>>>(ws, out);
  k_eig<<<Tc, 64, 0, stream>>>(ws, out);
  k_logits<<<dim3(NCH, Tc), 256, 0, stream>>>(ws, out);
  k_reduce<<<Tc, 64, 0, stream>>>(ws, out);
  k_norm<<<dim3(NCH, Tc), 256, 0, stream>>>(ws, out, 0);
  k_norm<<<dim3(NCH, Tc * Kc), 256, 0, stream>>>(ws, out, 1);
}

// Round 6
// 827.074 us; speedup vs baseline: 1.3550x; 1.0211x over previous
//
#include <hip/hip_runtime.h>
#include <math.h>

namespace {
constexpr int Vv  = 50257;
constexpr int Dc  = 128;
constexpr int Kc  = 3;
constexpr int NBc = 8;
constexpr int Jc  = 24;      // K*NB
constexpr int Tc  = 64;
constexpr int CHV = 1024;                      // vocab elems per block chunk
constexpr int NCH = (Vv + CHV - 1) / CHV;      // 50
constexpr float INV_SQRT_D = 0.08838834764831845f;
constexpr float DIVW = 2.0f;

// ws layout (float offsets)
constexpr size_t WS_PSI  = 0;        // 24*128
constexpr size_t WS_G    = 4096;     // 24*24 (psi gram)
constexpr size_t WS_BB   = 5120;     // 24*24 (raw bubble gram)
constexpr size_t WS_XN   = 6144;     // 64   |x_t|^2
constexpr size_t WS_BX   = 6400;     // 64*24 bub_j . x_t
constexpr size_t WS_WALL = 8192;     // 64*24
constexpr size_t WS_PART = 12288;    // 64*50*9 = 28800
constexpr size_t WS_LOGZ = 45056;    // 64*4
constexpr size_t WS_P2T  = 65536;    // 24*V  (transposed: [j][v] for coalescing)

// out layout (float offsets), reference return order
constexpr size_t OFF_TOK = 0;
constexpr size_t OFF_RHO = (size_t)Tc * Vv;
constexpr size_t OFF_S   = OFF_RHO + (size_t)Tc * Dc * Dc;
constexpr size_t OFF_H   = OFF_S + Tc;
constexpr size_t OFF_F   = OFF_H + Tc;
constexpr size_t OFF_PF  = OFF_F + Tc;
}

// ---- macro repeaters: named scalars defeat the alloca->scratch pathology ----
#define R12(X) X(0) X(1) X(2) X(3) X(4) X(5) X(6) X(7) X(8) X(9) X(10) X(11)
#define R12A(X,a) X(0,a) X(1,a) X(2,a) X(3,a) X(4,a) X(5,a) X(6,a) X(7,a) X(8,a) X(9,a) X(10,a) X(11,a)
#define R24(X) R12(X) X(12) X(13) X(14) X(15) X(16) X(17) X(18) X(19) X(20) X(21) X(22) X(23)
#define R24A(X,a) R12A(X,a) X(12,a) X(13,a) X(14,a) X(15,a) X(16,a) X(17,a) X(18,a) X(19,a) X(20,a) X(21,a) X(22,a) X(23,a)

__device__ __forceinline__ float wsum64(float v) {
#pragma unroll
  for (int m = 1; m < 64; m <<= 1) v += __shfl_xor(v, m);
  return v;
}

// online-softmax merge helpers
__device__ __forceinline__ void comb(float& m1, float& s1, float m2, float s2) {
  float M = fmaxf(m1, m2);
  float e1 = (s1 > 0.f) ? expf(m1 - M) : 0.f;
  float e2 = (s2 > 0.f) ? expf(m2 - M) : 0.f;
  s1 = s1 * e1 + s2 * e2;
  m1 = M;
}
__device__ __forceinline__ void comb_sl(float& m1, float& s1, float& sl1,
                                        float m2, float s2, float sl2) {
  float M = fmaxf(m1, m2);
  float e1 = (s1 > 0.f) ? expf(m1 - M) : 0.f;
  float e2 = (s2 > 0.f) ? expf(m2 - M) : 0.f;
  s1 = s1 * e1 + s2 * e2;
  sl1 = sl1 * e1 + sl2 * e2;
  m1 = M;
}

// ---------- psi + psi-Gram G + raw bubble Gram BB ----------
__global__ void k_prep(const float* __restrict__ bub, float* __restrict__ ws) {
  __shared__ float braw[Jc * Dc];
  __shared__ float psi[Jc * Dc];
  __shared__ float nrm[Jc];
  int tid = threadIdx.x;
  for (int i = tid; i < Jc * Dc; i += 256) braw[i] = bub[i];
  __syncthreads();
  if (tid < Jc) {
    float s = 0.f;
    for (int d = 0; d < Dc; ++d) { float b = braw[tid * Dc + d]; s += b * b; }
    nrm[tid] = sqrtf(s) + 1e-10f;
  }
  __syncthreads();
  for (int i = tid; i < Jc * Dc; i += 256) {
    float v = braw[i] / nrm[i / Dc];
    psi[i] = v;
    ws[WS_PSI + i] = v;
  }
  __syncthreads();
  for (int i = tid; i < Jc * Jc; i += 256) {
    int r = i / Jc, c = i % Jc;
    float g = 0.f, b = 0.f;
    for (int d = 0; d < Dc; ++d) {
      g += psi[r * Dc + d] * psi[c * Dc + d];
      b += braw[r * Dc + d] * braw[c * Dc + d];
    }
    ws[WS_G + i] = g;
    ws[WS_BB + i] = b;
  }
}

// ---------- per-token precompute: BX[t][j] = bub_j . E[tok_t], XN[t] = |x|^2 ----------
__global__ void __launch_bounds__(64, 1)
k_tok(const int* __restrict__ tok, const float* __restrict__ E,
      const float* __restrict__ bub, float* __restrict__ ws) {
  int t = blockIdx.x, lane = threadIdx.x;   // 64 threads = 1 wave
  int tk = tok[t];
  float eA = E[(size_t)tk * Dc + lane];
  float eB = E[(size_t)tk * Dc + 64 + lane];
  float xn = wsum64(eA * eA + eB * eB);
  if (lane == 0) ws[WS_XN + t] = xn;
#define TDECL(j) float p##j = bub[(j) * Dc + lane] * eA + bub[(j) * Dc + 64 + lane] * eB;
  R24(TDECL)
#undef TDECL
#define TRED(j,mm) p##j += __shfl_xor(p##j, mm);
  R24A(TRED, 1) R24A(TRED, 2) R24A(TRED, 4) R24A(TRED, 8) R24A(TRED, 16) R24A(TRED, 32)
#undef TRED
  if (lane == 0) {
#define TST(j) ws[WS_BX + (size_t)t * Jc + (j)] = p##j;
    R24(TST)
#undef TST
  }
}

// ---------- sequential recurrence, single wave, ALL state in named registers ----------
__global__ void __launch_bounds__(64, 1)
k_recur(const int* __restrict__ tok, const float* __restrict__ E,
        const float* __restrict__ bub, const float* __restrict__ pdb,
        const float* __restrict__ psn, float* __restrict__ ws) {
  __shared__ float sBX[Tc * Jc];
  __shared__ float sXN[Tc];
  int lane = threadIdx.x;                 // 64 threads = 1 wave
  for (int i = lane; i < Tc * Jc; i += 64) sBX[i] = ws[WS_BX + i];
  if (lane < Tc) sXN[lane] = ws[WS_XN + lane];
  float db = pdb[0];
  float sens = fabsf(psn[0]);
  int tokv = tok[lane];
  int jme = (lane < Jc) ? lane : (Jc - 1);
  int kme = jme >> 3;
  const float* bbr = ws + WS_BB + (size_t)jme * Jc;
  // raw bubbles (dims across lanes) + this lane's BB row — named scalars
#define RDECL(j) float bA##j = bub[(j) * Dc + lane], bB##j = bub[(j) * Dc + 64 + lane], BR##j = bbr[j];
  R24(RDECL)
#undef RDECL
  __syncthreads();
  float mA0 = 0.f, mA1 = 0.f, mA2 = 0.f, mB0 = 0.f, mB1 = 0.f, mB2 = 0.f;
  float BM0 = 0.f, BM1 = 0.f, BM2 = 0.f;
  int tk0 = __shfl(tokv, 0);
  float xA = E[(size_t)tk0 * Dc + lane];
  float xB = E[(size_t)tk0 * Dc + 64 + lane];
  for (int t = 0; t < Tc; ++t) {
    float nxA = 0.f, nxB = 0.f;
    if (t + 1 < Tc) {
      int nk = __shfl(tokv, t + 1);
      nxA = E[(size_t)nk * Dc + lane];
      nxB = E[(size_t)nk * Dc + 64 + lane];
    }
    // 6 butterfly reductions, interleaved for ILP
    float d0 = mA0 * xA + mB0 * xB, d1 = mA1 * xA + mB1 * xB, d2 = mA2 * xA + mB2 * xB;
    float n0 = mA0 * mA0 + mB0 * mB0, n1 = mA1 * mA1 + mB1 * mB1, n2 = mA2 * mA2 + mB2 * mB2;
#define RRED(mm) d0 += __shfl_xor(d0, mm); d1 += __shfl_xor(d1, mm); d2 += __shfl_xor(d2, mm); \
                 n0 += __shfl_xor(n0, mm); n1 += __shfl_xor(n1, mm); n2 += __shfl_xor(n2, mm);
    RRED(1) RRED(2) RRED(4) RRED(8) RRED(16) RRED(32)
#undef RRED
    float xn = sqrtf(sXN[t]) + 1e-10f;
    float mn0 = sqrtf(n0) + 1e-10f, mn1 = sqrtf(n1) + 1e-10f, mn2 = sqrtf(n2) + 1e-10f;
    float nov0 = (mn0 > 1e-8f) ? (1.f - d0 / (xn * mn0)) : 1.f;
    float nov1 = (mn1 > 1e-8f) ? (1.f - d1 / (xn * mn1)) : 1.f;
    float nov2 = (mn2 > 1e-8f) ? (1.f - d2 / (xn * mn2)) : 1.f;
    float dec0 = 1.f / (1.f + expf(-(db - sens * nov0)));
    float dec1 = 1.f / (1.f + expf(-(db - sens * nov1)));
    float dec2 = 1.f / (1.f + expf(-(db - sens * nov2)));
    float xmA0 = xA + dec0 * mA0, xmB0 = xB + dec0 * mB0;
    float xmA1 = xA + dec1 * mA1, xmB1 = xB + dec1 * mB1;
    float xmA2 = xA + dec2 * mA2, xmB2 = xB + dec2 * mB2;
    // scores + softmax over this lane's octet (j = lane for lane<24)
    float bxj = sBX[t * Jc + jme];
    float decS = (kme == 0) ? dec0 : ((kme == 1) ? dec1 : dec2);
    float BMS  = (kme == 0) ? BM0 : ((kme == 1) ? BM1 : BM2);
    float sc = (bxj + decS * BMS) * (DIVW * INV_SQRT_D);
    float mx = sc;
    mx = fmaxf(mx, __shfl_xor(mx, 1));
    mx = fmaxf(mx, __shfl_xor(mx, 2));
    mx = fmaxf(mx, __shfl_xor(mx, 4));
    float e = expf(sc - mx);
    float ss = e;
    ss += __shfl_xor(ss, 1);
    ss += __shfl_xor(ss, 2);
    ss += __shfl_xor(ss, 4);
    float w = e / ss;
    if (lane < Jc) ws[WS_WALL + (size_t)t * Jc + lane] = w;
    // broadcast all 24 weights (uniform-lane shfl -> readlane)
#define RWJ(j) float wj##j = __shfl(w, j);
    R24(RWJ)
#undef RWJ
    // mm' = dec*mm + (1-dec)/8*(xm + sum_n (1-w) bub)
    float aA0 = (1.f-wj0)*bA0 + (1.f-wj1)*bA1 + (1.f-wj2)*bA2 + (1.f-wj3)*bA3
              + (1.f-wj4)*bA4 + (1.f-wj5)*bA5 + (1.f-wj6)*bA6 + (1.f-wj7)*bA7;
    float aB0 = (1.f-wj0)*bB0 + (1.f-wj1)*bB1 + (1.f-wj2)*bB2 + (1.f-wj3)*bB3
              + (1.f-wj4)*bB4 + (1.f-wj5)*bB5 + (1.f-wj6)*bB6 + (1.f-wj7)*bB7;
    float aA1 = (1.f-wj8)*bA8 + (1.f-wj9)*bA9 + (1.f-wj10)*bA10 + (1.f-wj11)*bA11
              + (1.f-wj12)*bA12 + (1.f-wj13)*bA13 + (1.f-wj14)*bA14 + (1.f-wj15)*bA15;
    float aB1 = (1.f-wj8)*bB8 + (1.f-wj9)*bB9 + (1.f-wj10)*bB10 + (1.f-wj11)*bB11
              + (1.f-wj12)*bB12 + (1.f-wj13)*bB13 + (1.f-wj14)*bB14 + (1.f-wj15)*bB15;
    float aA2 = (1.f-wj16)*bA16 + (1.f-wj17)*bA17 + (1.f-wj18)*bA18 + (1.f-wj19)*bA19
              + (1.f-wj20)*bA20 + (1.f-wj21)*bA21 + (1.f-wj22)*bA22 + (1.f-wj23)*bA23;
    float aB2 = (1.f-wj16)*bB16 + (1.f-wj17)*bB17 + (1.f-wj18)*bB18 + (1.f-wj19)*bB19
              + (1.f-wj20)*bB20 + (1.f-wj21)*bB21 + (1.f-wj22)*bB22 + (1.f-wj23)*bB23;
    float od0 = (1.f - dec0) * 0.125f, od1 = (1.f - dec1) * 0.125f, od2 = (1.f - dec2) * 0.125f;
    mA0 = dec0 * mA0 + od0 * (xmA0 + aA0); mB0 = dec0 * mB0 + od0 * (xmB0 + aB0);
    mA1 = dec1 * mA1 + od1 * (xmA1 + aA1); mB1 = dec1 * mB1 + od1 * (xmB1 + aB1);
    mA2 = dec2 * mA2 + od2 * (xmA2 + aA2); mB2 = dec2 * mB2 + od2 * (xmB2 + aB2);
    // BM'[k] = dec*BM + (1-dec)/8*((bx + dec*BM) + sum_n (1-w) BB)
    float s20 = (1.f-wj0)*BR0 + (1.f-wj1)*BR1 + (1.f-wj2)*BR2 + (1.f-wj3)*BR3
              + (1.f-wj4)*BR4 + (1.f-wj5)*BR5 + (1.f-wj6)*BR6 + (1.f-wj7)*BR7;
    float s21 = (1.f-wj8)*BR8 + (1.f-wj9)*BR9 + (1.f-wj10)*BR10 + (1.f-wj11)*BR11
              + (1.f-wj12)*BR12 + (1.f-wj13)*BR13 + (1.f-wj14)*BR14 + (1.f-wj15)*BR15;
    float s22 = (1.f-wj16)*BR16 + (1.f-wj17)*BR17 + (1.f-wj18)*BR18 + (1.f-wj19)*BR19
              + (1.f-wj20)*BR20 + (1.f-wj21)*BR21 + (1.f-wj22)*BR22 + (1.f-wj23)*BR23;
    float bxm0 = bxj + dec0 * BM0, bxm1 = bxj + dec1 * BM1, bxm2 = bxj + dec2 * BM2;
    BM0 = dec0 * BM0 + (1.f - dec0) * 0.125f * (bxm0 + s20);
    BM1 = dec1 * BM1 + (1.f - dec1) * 0.125f * (bxm1 + s21);
    BM2 = dec2 * BM2 + (1.f - dec2) * 0.125f * (bxm2 + s22);
    xA = nxA; xB = nxB;
  }
}

// ---------- P2T[j][v] = (E[v] . psi_j)^2 ----------
__global__ void k_proj(const float* __restrict__ E, float* __restrict__ ws) {
  __shared__ float4 psi4[Jc][Dc / 4];
  int tid = threadIdx.x;
  for (int i = tid; i < Jc * Dc / 4; i += 256)
    ((float4*)psi4)[i] = ((const float4*)(ws + WS_PSI))[i];
  __syncthreads();
  int v = blockIdx.x * 256 + tid;
  if (v >= Vv) return;
  float acc[Jc];
#pragma unroll
  for (int j = 0; j < Jc; ++j) acc[j] = 0.f;
  const float4* e4 = (const float4*)(E + (size_t)v * Dc);
  for (int d = 0; d < Dc / 4; ++d) {
    float4 e = e4[d];
#pragma unroll
    for (int j = 0; j < Jc; ++j) {
      float4 p = psi4[j][d];
      acc[j] += e.x * p.x + e.y * p.y + e.z * p.z + e.w * p.w;
    }
  }
#pragma unroll
  for (int j = 0; j < Jc; ++j) ws[WS_P2T + (size_t)j * Vv + v] = acc[j] * acc[j];
}

// ---------- rho[t] = sum_j (w_j/3) psi_j psi_j^T  (one block per t) ----------
__global__ void k_rho(const float* __restrict__ ws, float* __restrict__ out) {
  int t = blockIdx.x;
  __shared__ float psis[Jc * Dc];
  __shared__ float wsh[Jc];
  int tid = threadIdx.x;
  for (int i = tid; i < Jc * Dc; i += 256) psis[i] = ws[WS_PSI + i];
  if (tid < Jc) wsh[tid] = ws[WS_WALL + (size_t)t * Jc + tid] * (1.f / 3.f);
  __syncthreads();
  int d = tid >> 1, eh = (tid & 1) * 64;
  float4 acc[16];
#pragma unroll
  for (int i = 0; i < 16; ++i) acc[i] = make_float4(0.f, 0.f, 0.f, 0.f);
  for (int j = 0; j < Jc; ++j) {
    float a = wsh[j] * psis[j * Dc + d];
    const float4* pr = (const float4*)&psis[j * Dc + eh];
#pragma unroll
    for (int i = 0; i < 16; ++i) {
      float4 p = pr[i];
      acc[i].x += a * p.x; acc[i].y += a * p.y; acc[i].z += a * p.z; acc[i].w += a * p.w;
    }
  }
  float* o = out + OFF_RHO + (size_t)t * Dc * Dc + (size_t)d * Dc + eh;
#pragma unroll
  for (int i = 0; i < 16; ++i) ((float4*)o)[i] = acc[i];
}

// ---------- S_rho[t]: one-sided Jacobi, Brent-Luk, ALL state in named registers ----------
__global__ void __launch_bounds__(64, 1)
k_eig(const float* __restrict__ ws, float* __restrict__ out) {
  int t = blockIdx.x;
  int lane = threadIdx.x;              // 64 threads = 1 wave
  const float* wall = ws + WS_WALL + (size_t)t * Jc;
  const float* psi = ws + WS_PSI;
#define EDECL(i) \
  float Tn##i = wall[2 * (i)] * (1.f / 3.f), Bn##i = wall[2 * (i) + 1] * (1.f / 3.f); \
  float sT##i = sqrtf(Tn##i), sQ##i = sqrtf(Bn##i); \
  float TA##i = psi[(2 * (i)) * Dc + lane] * sT##i; \
  float TB##i = psi[(2 * (i)) * Dc + 64 + lane] * sT##i; \
  float BA##i = psi[(2 * (i) + 1) * Dc + lane] * sQ##i; \
  float BB##i = psi[(2 * (i) + 1) * Dc + 64 + lane] * sQ##i;
  R12(EDECL)
#undef EDECL
  // slot-static Brent-Luk schedule: the round index never appears in the body
  for (int it = 0; it < 7 * 23; ++it) {
#define EDOT(i) float apq##i = TA##i * BA##i + TB##i * BB##i;
    R12(EDOT)
#undef EDOT
#define ERED(i,mm) apq##i += __shfl_xor(apq##i, mm);
    R12A(ERED, 1) R12A(ERED, 2) R12A(ERED, 4) R12A(ERED, 8) R12A(ERED, 16) R12A(ERED, 32)
#undef ERED
#define EROT(i) { \
      float a = apq##i, app = Tn##i, aqq = Bn##i; \
      float den = 2.f * a; den = (fabsf(den) < 1e-30f) ? 1e-30f : den; \
      float th = (aqq - app) / den; \
      float tt = 1.f / (fabsf(th) + sqrtf(1.f + th * th)); \
      tt = (th < 0.f) ? -tt : tt; \
      bool skip = fabsf(a) < 1e-12f; \
      float c = skip ? 1.f : 1.f / sqrtf(1.f + tt * tt); \
      float s = skip ? 0.f : tt * c; \
      float tu = skip ? 0.f : tt; \
      float ta = TA##i, tb = TB##i, ba = BA##i, bb = BB##i; \
      TA##i = c * ta - s * ba; BA##i = s * ta + c * ba; \
      TB##i = c * tb - s * bb; BB##i = s * tb + c * bb; \
      Tn##i = app - tu * a; Bn##i = aqq + tu * a; }
    R12(EROT)
#undef EROT
    // Brent-Luk rotation: top0 fixed; top shifts right, bottom shifts left
    {
      float zA = TA11, zB = TB11, zN = Tn11;
      TA11 = TA10; TB11 = TB10; Tn11 = Tn10;  TA10 = TA9; TB10 = TB9; Tn10 = Tn9;
      TA9 = TA8; TB9 = TB8; Tn9 = Tn8;        TA8 = TA7; TB8 = TB7; Tn8 = Tn7;
      TA7 = TA6; TB7 = TB6; Tn7 = Tn6;        TA6 = TA5; TB6 = TB5; Tn6 = Tn5;
      TA5 = TA4; TB5 = TB4; Tn5 = Tn4;        TA4 = TA3; TB4 = TB3; Tn4 = Tn3;
      TA3 = TA2; TB3 = TB2; Tn3 = Tn2;        TA2 = TA1; TB2 = TB1; Tn2 = Tn1;
      TA1 = BA0; TB1 = BB0; Tn1 = Bn0;
      BA0 = BA1; BB0 = BB1; Bn0 = Bn1;        BA1 = BA2; BB1 = BB2; Bn1 = Bn2;
      BA2 = BA3; BB2 = BB3; Bn2 = Bn3;        BA3 = BA4; BB3 = BB4; Bn3 = Bn4;
      BA4 = BA5; BB4 = BB5; Bn4 = Bn5;        BA5 = BA6; BB5 = BB6; Bn5 = Bn6;
      BA6 = BA7; BB6 = BB7; Bn6 = Bn7;        BA7 = BA8; BB7 = BB8; Bn7 = Bn8;
      BA8 = BA9; BB8 = BB9; Bn8 = Bn9;        BA9 = BA10; BB9 = BB10; Bn9 = Bn10;
      BA10 = BA11; BB10 = BB11; Bn10 = Bn11;
      BA11 = zA; BB11 = zB; Bn11 = zN;
    }
  }
  // entropy of {24 norms} U {104 x 1e-12 clipped zeros}
  float tot = (float)(Dc - Jc) * 1e-12f;
#define ESUM(i) tot += fmaxf(Tn##i, 1e-12f) + fmaxf(Bn##i, 1e-12f);
  R12(ESUM)
#undef ESUM
  float acc = 0.f;
#define EENT(i) { float p = fmaxf(Tn##i, 1e-12f) / tot; acc += p * logf(p); \
                  p = fmaxf(Bn##i, 1e-12f) / tot; acc += p * logf(p); }
  R12(EENT)
#undef EENT
  float pe = 1e-12f / tot;
  acc += (float)(Dc - Jc) * pe * logf(pe);
  if (lane == 0) out[OFF_S + t] = -acc;
}

// ---------- logits (stored into d_out prob regions) + online-softmax partials ----------
__global__ void k_logits(float* __restrict__ ws, float* __restrict__ out) {
  int ch = blockIdx.x, t = blockIdx.y, tid = threadIdx.x;
  __shared__ float wsh[Jc];
  __shared__ float rm[4][4], rs[4][4], rsl2[4];
  if (tid < Jc) wsh[tid] = ws[WS_WALL + (size_t)t * Jc + tid];
  __syncthreads();
  float m[4] = {-INFINITY, -INFINITY, -INFINITY, -INFINITY};
  float s[4] = {0.f, 0.f, 0.f, 0.f};
  float sl = 0.f;
  const float* p2 = ws + WS_P2T;
  for (int r = 0; r < 4; ++r) {
    int v = ch * CHV + r * 256 + tid;
    if (v >= Vv) break;
    float l0 = 0.f, l1 = 0.f, l2 = 0.f;
#pragma unroll
    for (int n = 0; n < NBc; ++n) {
      l0 += wsh[n]      * p2[(size_t)n * Vv + v];
      l1 += wsh[8 + n]  * p2[(size_t)(8 + n) * Vv + v];
      l2 += wsh[16 + n] * p2[(size_t)(16 + n) * Vv + v];
    }
    float l[4] = { l0, l1, l2, (l0 + l1 + l2) * (1.f / 3.f) };
    out[OFF_TOK + (size_t)t * Vv + v] = l[3];
    out[OFF_PF + ((size_t)t * Kc + 0) * Vv + v] = l0;
    out[OFF_PF + ((size_t)t * Kc + 1) * Vv + v] = l1;
    out[OFF_PF + ((size_t)t * Kc + 2) * Vv + v] = l2;
#pragma unroll
    for (int d = 0; d < 4; ++d) {
      float li = l[d];
      if (li > m[d]) {
        float e = expf(m[d] - li);
        s[d] = s[d] * e + 1.f;
        if (d == 3) sl = sl * e + li;
        m[d] = li;
      } else {
        float e = expf(li - m[d]);
        s[d] += e;
        if (d == 3) sl += e * li;
      }
    }
  }
#pragma unroll
  for (int off = 32; off; off >>= 1) {
#pragma unroll
    for (int d = 0; d < 3; ++d) {
      float om = __shfl_down(m[d], off);
      float os = __shfl_down(s[d], off);
      comb(m[d], s[d], om, os);
    }
    float om = __shfl_down(m[3], off);
    float os = __shfl_down(s[3], off);
    float osl = __shfl_down(sl, off);
    comb_sl(m[3], s[3], sl, om, os, osl);
  }
  int wv = tid >> 6, ln = tid & 63;
  if (ln == 0) {
#pragma unroll
    for (int d = 0; d < 4; ++d) { rm[wv][d] = m[d]; rs[wv][d] = s[d]; }
    rsl2[wv] = sl;
  }
  __syncthreads();
  if (tid == 0) {
    float* part = ws + WS_PART + ((size_t)t * NCH + ch) * 9;
    for (int d = 0; d < 3; ++d) {
      float M = rm[0][d], S = rs[0][d];
      for (int w2 = 1; w2 < 4; ++w2) comb(M, S, rm[w2][d], rs[w2][d]);
      part[d] = M; part[4 + d] = S;
    }
    float M = rm[0][3], S = rs[0][3], SL = rsl2[0];
    for (int w2 = 1; w2 < 4; ++w2) comb_sl(M, S, SL, rm[w2][3], rs[w2][3], rsl2[w2]);
    part[3] = M; part[7] = S; part[8] = SL;
  }
}

// ---------- merge chunk partials -> logZ[t][4]; H, F ----------
__global__ void k_reduce(float* __restrict__ ws, float* __restrict__ out) {
  int t = blockIdx.x, tid = threadIdx.x;
  if (tid < 4) {
    float M = -INFINITY, S = 0.f, SL = 0.f;
    for (int ch = 0; ch < NCH; ++ch) {
      const float* p = ws + WS_PART + ((size_t)t * NCH + ch) * 9;
      if (tid == 3) comb_sl(M, S, SL, p[3], p[7], p[8]);
      else          comb(M, S, p[tid], p[4 + tid]);
    }
    float lz = M + logf(S);
    ws[WS_LOGZ + (size_t)t * 4 + tid] = lz;
    if (tid == 3) {
      float H = lz - SL / S;
      float Srho = out[OFF_S + t];
      out[OFF_H + t] = H;
      out[OFF_F + t] = H - Srho;
    }
  }
}

// ---------- in-place logits -> probs ----------
__global__ void k_norm(const float* __restrict__ ws, float* __restrict__ out, int foam) {
  int row = blockIdx.y, ch = blockIdx.x, tid = threadIdx.x;
  size_t base; int lzi;
  if (foam) { int t = row / Kc, k = row % Kc; base = OFF_PF + (size_t)row * Vv; lzi = t * 4 + k; }
  else { base = OFF_TOK + (size_t)row * Vv; lzi = row * 4 + 3; }
  float lz = ws[WS_LOGZ + lzi];
  for (int r = 0; r < 4; ++r) {
    int v = ch * CHV + r * 256 + tid;
    if (v < Vv) out[base + v] = expf(out[base + v] - lz);
  }
}

extern "C" void kernel_launch(void* const* d_in, const int* in_sizes, int n_in,
                              void* d_out, int out_size, void* d_ws, size_t ws_size,
                              hipStream_t stream) {
  const int*   tokens = (const int*)d_in[0];
  const float* E      = (const float*)d_in[1];
  const float* bub    = (const float*)d_in[2];
  const float* pdb    = (const float*)d_in[3];
  const float* psn    = (const float*)d_in[4];
  float* out = (float*)d_out;
  float* ws  = (float*)d_ws;

  k_prep<<<1, 256, 0, stream>>>(bub, ws);
  k_proj<<<(Vv + 255) / 256, 256, 0, stream>>>(E, ws);
  k_tok<<<Tc, 64, 0, stream>>>(tokens, E, bub, ws);
  k_recur<<<1, 64, 0, stream>>>(tokens, E, bub, pdb, psn, ws);
  k_rho<<<Tc, 256, 0, stream>>>(ws, out);
  k_eig<<<Tc, 64, 0, stream>>>(ws, out);
  k_logits<<<dim3(NCH, Tc), 256, 0, stream>>>(ws, out);
  k_reduce<<<Tc, 64, 0, stream>>>(ws, out);
  k_norm<<<dim3(NCH, Tc), 256, 0, stream>>>(ws, out, 0);
  k_norm<<<dim3(NCH, Tc * Kc), 256, 0, stream>>>(ws, out, 1);
}